// Round 8
// baseline (8402.623 us; speedup 1.0000x reference)
//
#include <hip/hip_runtime.h>
#include <hip/hip_bf16.h>

// LSTM: N=640 seqs (B*Q fused), T=100, D=H=512. Inputs fp32; d_out FP32 (R4-verified).
// R8 = R7 with the staging-decomposition bug fixed (R7 NaN root cause: 64x256 LDS tile
// staged with the 64x128 slot split row=slot>>4/col=slot&15 -> OOB LDS writes dropped +
// half the tile never staged -> MFMA read uninitialized LDS -> NaN).
// Design (unchanged): (1) xg = x@Wih^T + b precomputed for all T as parallel MFMA GEMM,
// stored bf16 pre-swizzled in per-lane C/D fragment order; (2) one persistent kernel
// runs all 100 recurrent steps (320 blocks co-resident; 10 groups x 32 blocks with
// group-local atomic barriers; h ping-pong, release/acquire fences for cross-XCD
// visibility); (3) W_hh slice in VGPRs, cell state c in registers.

#define T_ 100
#define D_ 512
#define H_ 512
#define N_ 640
#define ASH 264  // LDS A-tile row stride (bf16 elems): 256 data + 8 pad

using short8  = __attribute__((ext_vector_type(8))) short;  // 8 bf16
using floatx4 = __attribute__((ext_vector_type(4))) float;  // MFMA C/D

__device__ __forceinline__ float sigmoidf_(float x) { return 1.0f / (1.0f + __expf(-x)); }

__device__ __forceinline__ unsigned short f2bf(float f) {  // RNE, finite inputs
    union { float f; unsigned int u; } v; v.f = f;
    unsigned int u = v.u;
    u += 0x7fffu + ((u >> 16) & 1u);
    return (unsigned short)(u >> 16);
}
__device__ __forceinline__ float bf2f(unsigned short b) {
    union { unsigned int u; float f; } v; v.u = ((unsigned int)b) << 16;
    return v.f;
}
__device__ __forceinline__ short8 cvt8(const float* __restrict__ p) {
    const float4 a = *(const float4*)p;
    const float4 b = *(const float4*)(p + 4);
    short8 r;
    r[0] = (short)f2bf(a.x); r[1] = (short)f2bf(a.y);
    r[2] = (short)f2bf(a.z); r[3] = (short)f2bf(a.w);
    r[4] = (short)f2bf(b.x); r[5] = (short)f2bf(b.y);
    r[6] = (short)f2bf(b.z); r[7] = (short)f2bf(b.w);
    return r;
}

__global__ __launch_bounds__(256) void cvt_bf16(const float* __restrict__ src,
                                                unsigned short* __restrict__ dst, int n) {
    const int i = (blockIdx.x * 256 + threadIdx.x) * 8;
    if (i < n) {
        const float4 a = *(const float4*)(src + i);
        const float4 b = *(const float4*)(src + i + 4);
        ushort4 o0, o1;
        o0.x = f2bf(a.x); o0.y = f2bf(a.y); o0.z = f2bf(a.z); o0.w = f2bf(a.w);
        o1.x = f2bf(b.x); o1.y = f2bf(b.y); o1.z = f2bf(b.z); o1.w = f2bf(b.w);
        *(ushort4*)(dst + i)     = o0;
        *(ushort4*)(dst + i + 4) = o1;
    }
}

// ---------------- xg = x @ Wih^T + (bih+bhh), bf16, swizzled [T][10][32][4][64][16] ----
__global__ __launch_bounds__(256, 2) void xg_gemm(
    const __hip_bfloat16* __restrict__ xb,   // [N][T][D] bf16
    const __hip_bfloat16* __restrict__ Wih,  // [2048][512] bf16
    const float* __restrict__ bih, const float* __restrict__ bhh,
    unsigned short* __restrict__ xg)
{
    __shared__ short A[64 * ASH];  // 33792 B
    const int tid = threadIdx.x, bid = blockIdx.x;
    const int grp = bid & 31;
    const int r2  = bid >> 5;      // 0..99
    const int sb  = r2 % 10;
    const int tc  = r2 / 10;       // 0..9
    const int gate = tid >> 6, lane = tid & 63, l15 = lane & 15, quad = lane >> 4;
    const int seq0 = sb * 64, hc0 = grp * 16;
    const int j4 = gate * H_ + hc0 + l15;

    short8 wf[16];
    {
        const __hip_bfloat16* wp = Wih + (size_t)j4 * D_ + quad * 8;
        #pragma unroll
        for (int ki = 0; ki < 16; ++ki) wf[ki] = *(const short8*)(wp + ki * 32);
    }
    const float bias = bih[j4] + bhh[j4];

    for (int tt = 0; tt < 10; ++tt) {
        const int t = tc * 10 + tt;
        floatx4 acc[4] = {};
        const __hip_bfloat16* ap = xb + (size_t)seq0 * (T_ * D_) + (size_t)t * D_;
        #pragma unroll
        for (int kc = 0; kc < 2; ++kc) {
            __syncthreads();
            // stage 64 rows x 256 cols: 2048 slots of 8 bf16 -> row=slot>>5, col=(slot&31)*8
            #pragma unroll
            for (int u = 0; u < 8; ++u) {
                const int slot = u * 256 + tid;
                const int row  = slot >> 5;
                const int col  = (slot & 31) * 8;
                *(short8*)&A[row * ASH + col] =
                    *(const short8*)(ap + (size_t)row * (T_ * D_) + kc * 256 + col);
            }
            __syncthreads();
            #pragma unroll
            for (int ki = 0; ki < 8; ++ki)
                #pragma unroll
                for (int mi = 0; mi < 4; ++mi) {
                    const short8 af = *(const short8*)&A[(mi * 16 + l15) * ASH + ki * 32 + quad * 8];
                    acc[mi] = __builtin_amdgcn_mfma_f32_16x16x32_bf16(af, wf[kc * 8 + ki], acc[mi], 0, 0, 0);
                }
        }
        short8 s0, s1;
        #pragma unroll
        for (int mi = 0; mi < 4; ++mi)
            #pragma unroll
            for (int rg = 0; rg < 4; ++rg) {
                const int e = mi * 4 + rg;
                const short v = (short)f2bf(acc[mi][rg] + bias);
                if (e < 8) s0[e] = v; else s1[e - 8] = v;
            }
        unsigned short* dst = xg + ((((size_t)t * 10 + sb) * 32 + grp) * 4 + gate) * 1024
                                 + (size_t)lane * 16;
        *(short8*)dst = s0;
        *(short8*)(dst + 8) = s1;
    }
}

// ---------------- persistent recurrent kernel: all 100 steps, group barriers --------
__global__ __launch_bounds__(256, 2) void lstm_persist(
    const unsigned short* __restrict__ xg,   // swizzled, includes biases
    const __hip_bfloat16* __restrict__ Whh,  // [2048][512] bf16
    __hip_bfloat16* __restrict__ h0,
    __hip_bfloat16* __restrict__ h1,
    float* __restrict__ out,                 // d_out fp32
    int* __restrict__ ctr)                   // 10 counters, 128 B apart, zeroed
{
    __shared__ short A[64 * ASH];   // h-staging chunks; G (16 KB fp32) aliases it
    float* G = (float*)A;

    const int tid = threadIdx.x, bid = blockIdx.x;
    const int grp = bid & 31, sb = bid >> 5;
    const int gate = tid >> 6, lane = tid & 63, l15 = lane & 15, quad = lane >> 4;
    const int seq0 = sb * 64, hc0 = grp * 16;

    short8 wf[16];  // W_hh slice in VGPRs, loaded once for all 100 steps
    {
        const __hip_bfloat16* wp = Whh + (size_t)(gate * H_ + hc0 + l15) * H_ + quad * 8;
        #pragma unroll
        for (int ki = 0; ki < 16; ++ki) wf[ki] = *(const short8*)(wp + ki * 32);
    }

    float c[4] = {0.f, 0.f, 0.f, 0.f};  // cell state in registers across all steps
    const unsigned short* xgp = xg + (((size_t)(sb * 32 + grp) * 4 + gate) * 64 + lane) * 16;
    int* cp = ctr + sb * 32;

    for (int t = 0; t < T_; ++t) {
        // xg fetch — independent of the group barrier, issued first
        const short8 x0 = *(const short8*)xgp;
        const short8 x1 = *(const short8*)(xgp + 8);
        xgp += (size_t)1310720;  // 10*32*4*64*16

        floatx4 acc[4];
        #pragma unroll
        for (int mi = 0; mi < 4; ++mi)
            #pragma unroll
            for (int rg = 0; rg < 4; ++rg) {
                const int e = mi * 4 + rg;
                acc[mi][rg] = bf2f((unsigned short)(e < 8 ? x0[e] : x1[e - 8]));
            }

        if (t > 0) {
            if (tid == 0) {
                while (__hip_atomic_load(cp, __ATOMIC_ACQUIRE, __HIP_MEMORY_SCOPE_AGENT) < 32 * t)
                    __builtin_amdgcn_s_sleep(2);
            }
            __syncthreads();
            __threadfence();  // acquire side: make remote h stores visible
            const __hip_bfloat16* hp = (t & 1) ? h0 : h1;  // buffer written at step t-1
            #pragma unroll
            for (int kc = 0; kc < 2; ++kc) {
                __syncthreads();  // protect A alias (prev G/A reads done)
                #pragma unroll
                for (int u = 0; u < 8; ++u) {
                    const int slot = u * 256 + tid;
                    const int row  = slot >> 5;
                    const int col  = (slot & 31) * 8;
                    *(short8*)&A[row * ASH + col] =
                        *(const short8*)(hp + (size_t)(seq0 + row) * H_ + kc * 256 + col);
                }
                __syncthreads();
                #pragma unroll
                for (int ki = 0; ki < 8; ++ki)
                    #pragma unroll
                    for (int mi = 0; mi < 4; ++mi) {
                        const short8 af = *(const short8*)&A[(mi * 16 + l15) * ASH + ki * 32 + quad * 8];
                        acc[mi] = __builtin_amdgcn_mfma_f32_16x16x32_bf16(af, wf[kc * 8 + ki], acc[mi], 0, 0, 0);
                    }
            }
            __syncthreads();  // A reads done before G writes (alias)
        }

        // G exchange (C/D: col=lane&15, row=quad*4+reg) + fused cell update
        #pragma unroll
        for (int mi = 0; mi < 4; ++mi)
            #pragma unroll
            for (int rg = 0; rg < 4; ++rg)
                G[gate * 1024 + (mi * 16 + quad * 4 + rg) * 16 + l15] = acc[mi][rg];
        __syncthreads();

        __hip_bfloat16* hw = (t & 1) ? h1 : h0;
        #pragma unroll
        for (int i = 0; i < 4; ++i) {
            const int e = tid + 256 * i, sl = e >> 4, col = e & 15;
            const float gi = sigmoidf_(G[0 * 1024 + sl * 16 + col]);
            const float gf = sigmoidf_(G[1 * 1024 + sl * 16 + col]);
            const float gg = tanhf   (G[2 * 1024 + sl * 16 + col]);
            const float go = sigmoidf_(G[3 * 1024 + sl * 16 + col]);
            const float cn = gf * c[i] + gi * gg;
            c[i] = cn;
            const float hv = go * tanhf(cn);
            const size_t idx = (size_t)(seq0 + sl) * H_ + hc0 + col;
            hw[idx] = __float2bfloat16(hv);
            if (t == T_ - 1) out[idx] = hv;
        }
        __threadfence();   // release: publish this thread's h stores
        __syncthreads();   // all threads' stores fenced before the group-visible add
        if (tid == 0)
            __hip_atomic_fetch_add(cp, 1, __ATOMIC_RELEASE, __HIP_MEMORY_SCOPE_AGENT);
    }
}

// ---------------- fallback (R6-verified path) for small ws --------------------------
__global__ __launch_bounds__(256) void lstm_step_fb(
    const float* __restrict__ x,
    const __hip_bfloat16* __restrict__ Wih, const __hip_bfloat16* __restrict__ Whh,
    const float* __restrict__ bih, const float* __restrict__ bhh,
    const __hip_bfloat16* __restrict__ hprev, __hip_bfloat16* __restrict__ hnext,
    float* __restrict__ cbuf, float* __restrict__ out, int t)
{
    __shared__ __hip_bfloat16 Af[64 * 136];
    __shared__ float Gf[4][64][16];
    const int tid = threadIdx.x, bid = blockIdx.x;
    const int grp = bid & 31, sb = bid >> 5;
    const int gate = tid >> 6, lane = tid & 63, l15 = lane & 15, quad = lane >> 4;
    const int seq0 = sb * 64, hc0 = grp * 16;
    const int r = gate * H_ + hc0 + l15;
    floatx4 acc[4] = {};
    #pragma unroll
    for (int phase = 0; phase < 2; ++phase) {
        const __hip_bfloat16* ab = nullptr; const float* af = nullptr; size_t astr;
        if (phase == 0) { astr = (size_t)T_ * D_; af = x + (size_t)seq0 * astr + (size_t)t * D_; }
        else            { astr = H_;              ab = hprev + (size_t)seq0 * H_; }
        const __hip_bfloat16* wp = (phase ? Whh : Wih) + (size_t)r * 512 + quad * 8;
        for (int kc = 0; kc < 512; kc += 128) {
            __syncthreads();
            #pragma unroll
            for (int u = 0; u < 4; ++u) {
                const int slot = u * 256 + tid, row = slot >> 4, c16 = slot & 15;
                short8 v;
                if (phase == 0) v = cvt8(af + row * astr + kc + c16 * 8);
                else            v = *(const short8*)(ab + row * astr + kc + c16 * 8);
                *(short8*)&Af[row * 136 + c16 * 8] = v;
            }
            __syncthreads();
            #pragma unroll
            for (int ki = 0; ki < 4; ++ki) {
                const short8 bfrag = *(const short8*)(wp + kc + ki * 32);
                #pragma unroll
                for (int mi = 0; mi < 4; ++mi) {
                    const short8 afr = *(const short8*)&Af[(mi * 16 + l15) * 136 + ki * 32 + quad * 8];
                    acc[mi] = __builtin_amdgcn_mfma_f32_16x16x32_bf16(afr, bfrag, acc[mi], 0, 0, 0);
                }
            }
        }
    }
    #pragma unroll
    for (int mi = 0; mi < 4; ++mi)
        #pragma unroll
        for (int rg = 0; rg < 4; ++rg)
            Gf[gate][mi * 16 + quad * 4 + rg][l15] = acc[mi][rg];
    __syncthreads();
    #pragma unroll
    for (int i = 0; i < 4; ++i) {
        const int e = tid + 256 * i, sl = e >> 4, col = e & 15;
        const int n = seq0 + sl, j = hc0 + col;
        const float bi = bih[j] + bhh[j];
        const float bf = bih[H_ + j] + bhh[H_ + j];
        const float bg = bih[2 * H_ + j] + bhh[2 * H_ + j];
        const float bo = bih[3 * H_ + j] + bhh[3 * H_ + j];
        const float gi = sigmoidf_(Gf[0][sl][col] + bi);
        const float gf = sigmoidf_(Gf[1][sl][col] + bf);
        const float gg = tanhf(Gf[2][sl][col] + bg);
        const float go = sigmoidf_(Gf[3][sl][col] + bo);
        const int idx = n * H_ + j;
        const float cn = gf * cbuf[idx] + gi * gg;
        cbuf[idx] = cn;
        const float hv = go * tanhf(cn);
        hnext[idx] = __float2bfloat16(hv);
        if (out) out[idx] = hv;
    }
}

extern "C" void kernel_launch(void* const* d_in, const int* in_sizes, int n_in,
                              void* d_out, int out_size, void* d_ws, size_t ws_size,
                              hipStream_t stream) {
    const float* x    = (const float*)d_in[0];
    const float* Wihf = (const float*)d_in[1];
    const float* Whhf = (const float*)d_in[2];
    const float* bih  = (const float*)d_in[3];
    const float* bhh  = (const float*)d_in[4];

    const size_t nW = (size_t)4 * H_ * D_;        // 1,048,576
    const size_t nX = (size_t)N_ * T_ * D_;       // 32,768,000
    const size_t nH = (size_t)N_ * H_;            // 327,680
    const size_t nXG = (size_t)T_ * N_ * 4 * H_;  // 131,072,000

    // fast-path ws layout: ctr | Wb | Ub | xb | xg | h0 | h1   (~333 MB)
    const size_t need = 4096 + nW * 2 * 2 + nX * 2 + nXG * 2 + nH * 2 * 2;

    if (ws_size >= need) {
        char* p = (char*)d_ws;
        int* ctr = (int*)p;                        p += 4096;
        __hip_bfloat16* Wb = (__hip_bfloat16*)p;   p += nW * 2;
        __hip_bfloat16* Ub = (__hip_bfloat16*)p;   p += nW * 2;
        __hip_bfloat16* xb = (__hip_bfloat16*)p;   p += nX * 2;
        unsigned short* xg = (unsigned short*)p;   p += nXG * 2;
        __hip_bfloat16* h0 = (__hip_bfloat16*)p;   p += nH * 2;
        __hip_bfloat16* h1 = (__hip_bfloat16*)p;

        hipMemsetAsync(ctr, 0, 4096, stream);
        cvt_bf16<<<(int)(nW / 2048), 256, 0, stream>>>(Wihf, (unsigned short*)Wb, (int)nW);
        cvt_bf16<<<(int)(nW / 2048), 256, 0, stream>>>(Whhf, (unsigned short*)Ub, (int)nW);
        cvt_bf16<<<(int)(nX / 2048), 256, 0, stream>>>(x, (unsigned short*)xb, (int)nX);

        xg_gemm<<<3200, 256, 0, stream>>>(xb, Wb, bih, bhh, xg);
        lstm_persist<<<320, 256, 0, stream>>>(xg, Ub, h0, h1, (float*)d_out, ctr);
    } else {
        // fallback: R6-verified per-step path (~7 MB ws)
        char* p = (char*)d_ws;
        __hip_bfloat16* Wb = (__hip_bfloat16*)p;   p += nW * 2;
        __hip_bfloat16* Ub = (__hip_bfloat16*)p;   p += nW * 2;
        __hip_bfloat16* h0 = (__hip_bfloat16*)p;   p += nH * 2;
        __hip_bfloat16* h1 = (__hip_bfloat16*)p;   p += nH * 2;
        float* cbuf = (float*)p;

        cvt_bf16<<<(int)(nW / 2048), 256, 0, stream>>>(Wihf, (unsigned short*)Wb, (int)nW);
        cvt_bf16<<<(int)(nW / 2048), 256, 0, stream>>>(Whhf, (unsigned short*)Ub, (int)nW);
        hipMemsetAsync(h0, 0, nH * 2, stream);
        hipMemsetAsync(cbuf, 0, nH * 4, stream);
        for (int t = 0; t < T_; ++t) {
            const __hip_bfloat16* hp = (t & 1) ? h1 : h0;
            __hip_bfloat16* hn       = (t & 1) ? h0 : h1;
            float* o = (t == T_ - 1) ? (float*)d_out : nullptr;
            lstm_step_fb<<<320, 256, 0, stream>>>(x, Wb, Ub, bih, bhh, hp, hn, cbuf, o, t);
        }
    }
}